// Round 13
// baseline (503.688 us; speedup 1.0000x reference)
//
#include <hip/hip_runtime.h>
#include <math.h>

#define SB 32          // samples per block (8 per wave, 4 waves)
#define NTHREADS 256

typedef short short8 __attribute__((ext_vector_type(8)));
typedef float f32x4  __attribute__((ext_vector_type(4)));

__device__ __forceinline__ unsigned short f2bf(float f) {
    unsigned int u = __builtin_bit_cast(unsigned int, f);
    unsigned int r = (u + 0x7FFFu + ((u >> 16) & 1u)) >> 16;   // RNE
    return (unsigned short)r;
}
__device__ __forceinline__ float bf2f(unsigned short h) {
    unsigned int u = ((unsigned int)h) << 16;
    return __builtin_bit_cast(float, u);
}
__device__ __forceinline__ unsigned pack2(unsigned short lo, unsigned short hi) {
    return (unsigned)lo | ((unsigned)hi << 16);
}
__device__ __forceinline__ float softplus_f(float z) {
    return z > 15.f ? z : log1pf(expf(z));
}
__device__ __forceinline__ float fast_tanh(float z) {
    const float e = __builtin_amdgcn_exp2f(z * 2.8853900817779268f);
    return fmaf(-2.f, __builtin_amdgcn_rcpf(e + 1.f), 1.f);
}
__device__ __forceinline__ unsigned selv(bool c, unsigned a, unsigned b) {
    return c ? a : b;
}
__device__ __forceinline__ unsigned sx(unsigned v, int m) {
    return (unsigned)__shfl_xor((int)v, m);
}

// ---------------- prep: pack W1 (split hi/lo) + W0 + head weights ----------------
// wB (uint4 slots): nt*1024 + [hi: ks*64+l | lo: 512+ks*64+l]
// slot element i: B[k][n], k = ks*32 + (l>>4)*8 + i, n = nt*16 + (l&15)
__global__ void prep(const float* __restrict__ W1, const float* __restrict__ W0,
                     const float* __restrict__ Wd, const float* __restrict__ Wo,
                     const float* __restrict__ Wv,
                     unsigned short* __restrict__ wB,
                     float4* __restrict__ w0p, float4* __restrict__ hwp)
{
    int idx = blockIdx.x * blockDim.x + threadIdx.x;
    if (idx < 256) {
        w0p[idx] = make_float4(W0[idx], W0[256 + idx], W0[512 + idx], W0[768 + idx]);
        hwp[idx] = make_float4(Wd[2 * idx], Wd[2 * idx + 1], Wo[idx], Wv[idx]);
    }
    if (idx < 8192) {
        const int l  = idx & 63;
        const int ks = (idx >> 6) & 7;
        const int nt = idx >> 9;
        const int k0 = ks * 32 + (l >> 4) * 8;
        const int n  = nt * 16 + (l & 15);
        const int hbase = (nt * 1024 + ks * 64 + l) * 8;
        const int lbase = (nt * 1024 + 512 + ks * 64 + l) * 8;
        #pragma unroll
        for (int i = 0; i < 8; ++i) {
            const float f = W1[(k0 + i) * 256 + n];
            const unsigned short hi = f2bf(f);
            const unsigned short lo = f2bf(f - bf2f(hi));
            wB[hbase + i] = hi;
            wB[lbase + i] = lo;
        }
    }
}

// Build one 16-row A fragment set (rows = rho*4+s: h_hi,h_lo,ta,tb x 4 samples).
// Identical arithmetic + exchange (xor 4/8/12) to the r9-passing kernel.
__device__ __forceinline__ void build_aF(
    const float4* __restrict__ w0p, const float* __restrict__ b0,
    int kg, int rho, bool rb0, bool rb1,
    float sn0, float cs0, float sn1, float cs1, short8* aF)
{
    #pragma unroll
    for (int ks = 0; ks < 8; ++ks) {
        const int j0 = ks * 32 + kg * 8 + 2 * rho;
        const float4 wa = w0p[j0];
        const float4 wb = w0p[j0 + 1];
        const float2 bb = *reinterpret_cast<const float2*>(&b0[j0]);
        float z0 = bb.x;
        z0 = fmaf(cs0, wa.x, z0); z0 = fmaf(cs1, wa.y, z0);
        z0 = fmaf(sn0, wa.z, z0); z0 = fmaf(sn1, wa.w, z0);
        float z1 = bb.y;
        z1 = fmaf(cs0, wb.x, z1); z1 = fmaf(cs1, wb.y, z1);
        z1 = fmaf(sn0, wb.z, z1); z1 = fmaf(sn1, wb.w, z1);
        const float h0 = fast_tanh(z0);
        const float h1 = fast_tanh(z1);
        const unsigned short h0h = f2bf(h0);
        const unsigned short h1h = f2bf(h1);
        const unsigned short h0l = f2bf(h0 - bf2f(h0h));
        const unsigned short h1l = f2bf(h1 - bf2f(h1h));
        const float dt0 = fmaf(-h0, h0, 1.f);
        const float dt1 = fmaf(-h1, h1, 1.f);
        const float ta0 = dt0 * fmaf(-sn0, wa.x, cs0 * wa.z);
        const float ta1 = dt1 * fmaf(-sn0, wb.x, cs0 * wb.z);
        const float tb0 = dt0 * fmaf(-sn1, wa.y, cs1 * wa.w);
        const float tb1 = dt1 * fmaf(-sn1, wb.y, cs1 * wb.w);
        const unsigned v0 = pack2(h0h, h1h);
        const unsigned v1 = pack2(h0l, h1l);
        const unsigned v2 = pack2(f2bf(ta0), f2bf(ta1));
        const unsigned v3 = pack2(f2bf(tb0), f2bf(tb1));
        const unsigned s0 = selv(rb1, selv(rb0, v3, v2), selv(rb0, v1, v0));
        const unsigned s1 = selv(rb1, selv(rb0, v2, v3), selv(rb0, v0, v1));
        const unsigned s2 = selv(rb1, selv(rb0, v1, v0), selv(rb0, v3, v2));
        const unsigned s3 = selv(rb1, selv(rb0, v0, v1), selv(rb0, v2, v3));
        const unsigned r4  = sx(s1, 4);
        const unsigned r8  = sx(s2, 8);
        const unsigned r12 = sx(s3, 12);
        const unsigned w0 = selv(rb1, selv(rb0, r12, r8), selv(rb0, r4, s0));
        const unsigned w1 = selv(rb1, selv(rb0, r8, r12), selv(rb0, s0, r4));
        const unsigned w2 = selv(rb1, selv(rb0, r4, s0), selv(rb0, r12, r8));
        const unsigned w3 = selv(rb1, selv(rb0, s0, r4), selv(rb0, r8, r12));
        aF[ks] = __builtin_bit_cast(short8, make_uint4(w0, w1, w2, w3));
    }
}

// r9's quadrant-dedup'd epilogue accumulation (1 tanh/lane/call).
__device__ __forceinline__ void epi_acc(
    const f32x4& c1, const f32x4& c2, float b1v, const float4& hw,
    bool qb0, bool qb1, bool qlt2,
    float* u0, float* u1, float* u2, float* u3)
{
    float zs[4], zf[4], zA[4];
    #pragma unroll
    for (int r = 0; r < 4; ++r) zs[r] = c1[r] + c2[r];
    #pragma unroll
    for (int r = 0; r < 4; ++r) zf[r] = zs[r] + __shfl_xor(zs[r], 16) + b1v;
    #pragma unroll
    for (int r = 0; r < 4; ++r) {
        const float zr = __shfl_xor(zf[r], 32);
        zA[r] = qlt2 ? zf[r] : zr;
    }
    const float zpick = qb1 ? (qb0 ? zA[3] : zA[2]) : (qb0 ? zA[1] : zA[0]);
    const float hq = fast_tanh(zpick);
    const float g1 = __shfl_xor(hq, 16);
    const float g2 = __shfl_xor(hq, 32);
    const float g3 = __shfl_xor(hq, 48);
    float hr[4];
    hr[0] = qb1 ? (qb0 ? g3 : g2) : (qb0 ? g1 : hq);
    hr[1] = qb1 ? (qb0 ? g2 : g3) : (qb0 ? hq : g1);
    hr[2] = qb1 ? (qb0 ? g1 : hq) : (qb0 ? g3 : g2);
    hr[3] = qb1 ? (qb0 ? hq : g1) : (qb0 ? g2 : g3);
    #pragma unroll
    for (int r = 0; r < 4; ++r) {
        const float dt  = fmaf(-hr[r], hr[r], 1.f);
        const float val = qlt2 ? hr[r] : dt * zs[r];
        u0[r] = fmaf(val, hw.x, u0[r]);
        u1[r] = fmaf(val, hw.y, u1[r]);
        u2[r] = fmaf(val, hw.z, u2[r]);
        u3[r] = fmaf(val, hw.w, u3[r]);
    }
}

// scalar per-sample dynamics solve + output write (r9 body)
__device__ __forceinline__ void solve_write(
    const float* __restrict__ x, float* __restrict__ out, int sg,
    float phd0, float phd1, float phoo,
    float pad0, float pad1, float pao, float pav,
    float pbd0, float pbd1, float pbo, float pbv,
    float bd0, float bd1, float bo0)
{
    const float u    = x[sg * 6 + 2];
    const float vv   = x[sg * 6 + 3];
    const float tau0 = x[sg * 6 + 4];
    const float tau1 = x[sg * 6 + 5];

    const float zd0 = phd0 + bd0;
    const float zd1 = phd1 + bd1;
    const float zo  = phoo + bo0;

    const float ld0 = softplus_f(zd0) + 1e-4f;
    const float ld1 = softplus_f(zd1) + 1e-4f;
    const float lo  = zo;

    const float sg0 = 1.f / (1.f + expf(-zd0));
    const float sg1 = 1.f / (1.f + expf(-zd1));

    const float ld0a = sg0 * pad0, ld0b = sg0 * pbd0;
    const float ld1a = sg1 * pad1, ld1b = sg1 * pbd1;
    const float loa  = pao,        lob  = pbo;
    const float ga   = pav,        gb   = pbv;

    const float H00 = fmaf(ld0, ld0, 1e-4f);
    const float H01 = ld0 * lo;
    const float H11 = fmaf(lo, lo, fmaf(ld1, ld1, 1e-4f));

    const float dH00a = 2.f * ld0 * ld0a, dH00b = 2.f * ld0 * ld0b;
    const float dH01a = fmaf(ld0a, lo, ld0 * loa);
    const float dH01b = fmaf(ld0b, lo, ld0 * lob);
    const float dH11a = 2.f * fmaf(lo, loa, ld1 * ld1a);
    const float dH11b = 2.f * fmaf(lo, lob, ld1 * ld1b);

    const float wa0 = fmaf(dH00a, u, dH01a * vv);
    const float wa1 = fmaf(dH01a, u, dH11a * vv);
    const float wb0 = fmaf(dH00b, u, dH01b * vv);
    const float wb1 = fmaf(dH01b, u, dH11b * vv);

    const float QFa = dH00a*u*u + 2.f*dH01a*u*vv + dH11a*vv*vv;
    const float QFb = dH00b*u*u + 2.f*dH01b*u*vv + dH11b*vv*vv;

    const float C0 = fmaf(wa0, u, wb0 * vv) - 0.5f * QFa;
    const float C1 = fmaf(wa1, u, wb1 * vv) - 0.5f * QFb;

    const float r0 = tau0 - C0 - ga;
    const float r1 = tau1 - C1 - gb;

    const float det = fmaf(H00, H11, -H01 * H01);
    const float inv = 1.f / det;
    const float qdd0 = (H11 * r0 - H01 * r1) * inv;
    const float qdd1 = (H00 * r1 - H01 * r0) * inv;

    float2* o = reinterpret_cast<float2*>(&out[sg * 6]);
    o[0] = make_float2(u, vv);
    o[1] = make_float2(qdd0, qdd1);
    o[2] = make_float2(0.f, 0.f);
}

__global__ __launch_bounds__(NTHREADS, 5)
void lode_mfma(const float* __restrict__ x,
               const float4* __restrict__ w0p, const float* __restrict__ b0,
               const unsigned short* __restrict__ wB,
               const float* __restrict__ b1,
               const float4* __restrict__ hwp,
               const float* __restrict__ bd, const float* __restrict__ bo,
               float* __restrict__ out, int n)
{
    __shared__ uint4 S[2048];   // 32 KB B double-buffer

    const int tid  = threadIdx.x;
    const int wave = tid >> 6;
    const int lane = tid & 63;
    const int r15  = lane & 15;
    const int s    = r15 & 3;
    const int rho  = r15 >> 2;
    const bool rb0 = (rho & 1) != 0;
    const bool rb1 = (rho & 2) != 0;
    const int kg   = lane >> 4;

    // ---------------- phase 1: two A-fragment sets (samples wave*8+s / +4+s) ----
    int sgA = blockIdx.x * SB + wave * 8 + s;
    int sgB = sgA + 4;
    if (sgA >= n) sgA = n - 1;
    if (sgB >= n) sgB = n - 1;
    const float qA0 = x[sgA * 6 + 0];
    const float qA1 = x[sgA * 6 + 1];
    const float qB0 = x[sgB * 6 + 0];
    const float qB1 = x[sgB * 6 + 1];
    float ssA, ccA, ssB, ccB;
    sincosf(rb0 ? qA1 : qA0, &ssA, &ccA);
    sincosf(rb0 ? qB1 : qB0, &ssB, &ccB);
    const float ssAo = __shfl_xor(ssA, 4), ccAo = __shfl_xor(ccA, 4);
    const float ssBo = __shfl_xor(ssB, 4), ccBo = __shfl_xor(ccB, 4);
    const float snA0 = rb0 ? ssAo : ssA, csA0 = rb0 ? ccAo : ccA;
    const float snA1 = rb0 ? ssA : ssAo, csA1 = rb0 ? ccA : ccAo;
    const float snB0 = rb0 ? ssBo : ssB, csB0 = rb0 ? ccBo : ccB;
    const float snB1 = rb0 ? ssB : ssBo, csB1 = rb0 ? ccB : ccBo;

    short8 aFA[8], aFB[8];
    build_aF(w0p, b0, kg, rho, rb0, rb1, snA0, csA0, snA1, csA1, aFA);
    build_aF(w0p, b0, kg, rho, rb0, rb1, snB0, csB0, snB1, csB1, aFB);

    // ---------------- stage nt=0 into buffer 0 (r7 4-wave pattern) ----------------
    {
        const char* src = (const char*)wB;
        #pragma unroll
        for (int g = 0; g < 4; ++g) {
            const int chunk = g * 4 + wave;
            __builtin_amdgcn_global_load_lds(
                (const __attribute__((address_space(1))) void*)(src + chunk * 1024 + lane * 16),
                (__attribute__((address_space(3))) void*)&S[chunk * 64 + lane], 16, 0, 0);
        }
    }
    __syncthreads();

    float uA0[4] = {0,0,0,0}, uA1[4] = {0,0,0,0}, uA2[4] = {0,0,0,0}, uA3[4] = {0,0,0,0};
    float uB0[4] = {0,0,0,0}, uB1[4] = {0,0,0,0}, uB2[4] = {0,0,0,0}, uB3[4] = {0,0,0,0};
    const int col = lane & 15;
    const int q   = lane >> 4;
    const bool qb0 = (q & 1) != 0;
    const bool qb1 = (q & 2) != 0;
    const bool qlt2 = (q < 2);

    #pragma unroll 1
    for (int nt = 0; nt < 16; ++nt) {
        // prefetch nt+1 into the other buffer (wraps harmlessly at nt=15)
        {
            const int ntn = (nt + 1) & 15;
            const int bn  = (nt + 1) & 1;
            const char* src = (const char*)wB + ntn * 16384;
            #pragma unroll
            for (int g = 0; g < 4; ++g) {
                const int chunk = g * 4 + wave;
                __builtin_amdgcn_global_load_lds(
                    (const __attribute__((address_space(1))) void*)(src + chunk * 1024 + lane * 16),
                    (__attribute__((address_space(3))) void*)&S[bn * 1024 + chunk * 64 + lane],
                    16, 0, 0);
            }
        }

        const int ncol = nt * 16 + col;
        const float4 hw  = hwp[ncol];
        const float  b1v = b1[ncol];

        const uint4* Bb = &S[(nt & 1) * 1024];
        f32x4 c1A = {0.f,0.f,0.f,0.f}, c2A = {0.f,0.f,0.f,0.f};
        f32x4 c1B = {0.f,0.f,0.f,0.f}, c2B = {0.f,0.f,0.f,0.f};
        #pragma unroll
        for (int ks = 0; ks < 8; ++ks) {
            const short8 bh = *reinterpret_cast<const short8*>(&Bb[ks * 64 + lane]);
            const short8 bl = *reinterpret_cast<const short8*>(&Bb[512 + ks * 64 + lane]);
            c1A = __builtin_amdgcn_mfma_f32_16x16x32_bf16(aFA[ks], bh, c1A, 0, 0, 0);
            c2A = __builtin_amdgcn_mfma_f32_16x16x32_bf16(aFA[ks], bl, c2A, 0, 0, 0);
            c1B = __builtin_amdgcn_mfma_f32_16x16x32_bf16(aFB[ks], bh, c1B, 0, 0, 0);
            c2B = __builtin_amdgcn_mfma_f32_16x16x32_bf16(aFB[ks], bl, c2B, 0, 0, 0);
        }

        epi_acc(c1A, c2A, b1v, hw, qb0, qb1, qlt2, uA0, uA1, uA2, uA3);
        epi_acc(c1B, c2B, b1v, hw, qb0, qb1, qlt2, uB0, uB1, uB2, uB3);
        __syncthreads();
    }

    // ---------------- column reduction across the 16 cols ----------------
    #pragma unroll
    for (int r = 0; r < 4; ++r) {
        #pragma unroll
        for (int m = 1; m < 16; m <<= 1) {
            uA0[r] += __shfl_xor(uA0[r], m);
            uA1[r] += __shfl_xor(uA1[r], m);
            uA2[r] += __shfl_xor(uA2[r], m);
            uA3[r] += __shfl_xor(uA3[r], m);
            uB0[r] += __shfl_xor(uB0[r], m);
            uB1[r] += __shfl_xor(uB1[r], m);
            uB2[r] += __shfl_xor(uB2[r], m);
            uB3[r] += __shfl_xor(uB3[r], m);
        }
    }
    // gather tangent sums onto q0: pa from q2 (xor32), pb from q3 (xor48)
    float paA0[4], paA1[4], paA2[4], paA3[4], pbA0[4], pbA1[4], pbA2[4], pbA3[4];
    float paB0[4], paB1[4], paB2[4], paB3[4], pbB0[4], pbB1[4], pbB2[4], pbB3[4];
    #pragma unroll
    for (int r = 0; r < 4; ++r) {
        paA0[r] = __shfl_xor(uA0[r], 32);
        paA1[r] = __shfl_xor(uA1[r], 32);
        paA2[r] = __shfl_xor(uA2[r], 32);
        paA3[r] = __shfl_xor(uA3[r], 32);
        pbA0[r] = __shfl_xor(uA0[r], 48);
        pbA1[r] = __shfl_xor(uA1[r], 48);
        pbA2[r] = __shfl_xor(uA2[r], 48);
        pbA3[r] = __shfl_xor(uA3[r], 48);
        paB0[r] = __shfl_xor(uB0[r], 32);
        paB1[r] = __shfl_xor(uB1[r], 32);
        paB2[r] = __shfl_xor(uB2[r], 32);
        paB3[r] = __shfl_xor(uB3[r], 32);
        pbB0[r] = __shfl_xor(uB0[r], 48);
        pbB1[r] = __shfl_xor(uB1[r], 48);
        pbB2[r] = __shfl_xor(uB2[r], 48);
        pbB3[r] = __shfl_xor(uB3[r], 48);
    }

    if (lane == 0) {
        const float bd0 = bd[0], bd1 = bd[1], bo0 = bo[0];
        const int base = blockIdx.x * SB + wave * 8;
        #pragma unroll
        for (int r = 0; r < 4; ++r) {
            if (base + r < n)
                solve_write(x, out, base + r,
                            uA0[r], uA1[r], uA2[r],
                            paA0[r], paA1[r], paA2[r], paA3[r],
                            pbA0[r], pbA1[r], pbA2[r], pbA3[r], bd0, bd1, bo0);
            if (base + 4 + r < n)
                solve_write(x, out, base + 4 + r,
                            uB0[r], uB1[r], uB2[r],
                            paB0[r], paB1[r], paB2[r], paB3[r],
                            pbB0[r], pbB1[r], pbB2[r], pbB3[r], bd0, bd1, bo0);
        }
    }
}

extern "C" void kernel_launch(void* const* d_in, const int* in_sizes, int n_in,
                              void* d_out, int out_size, void* d_ws, size_t ws_size,
                              hipStream_t stream) {
    // dict order: t, x, W0, b0, W1, b1, Wd, bd, Wo, bo, Wv, bv
    const float* x  = (const float*)d_in[1];
    const float* W0 = (const float*)d_in[2];
    const float* b0 = (const float*)d_in[3];
    const float* W1 = (const float*)d_in[4];
    const float* b1 = (const float*)d_in[5];
    const float* Wd = (const float*)d_in[6];
    const float* bd = (const float*)d_in[7];
    const float* Wo = (const float*)d_in[8];
    const float* bo = (const float*)d_in[9];
    const float* Wv = (const float*)d_in[10];
    float* out = (float*)d_out;

    unsigned short* wB = (unsigned short*)d_ws;                         // 256 KB
    float4* w0p = (float4*)((char*)d_ws + 262144);                      // 4 KB
    float4* hwp = (float4*)((char*)d_ws + 262144 + 4096);               // 4 KB

    const int n = in_sizes[1] / 6;

    prep<<<32, 256, 0, stream>>>(W1, W0, Wd, Wo, Wv, wB, w0p, hwp);

    const int grid = (n + SB - 1) / SB;
    lode_mfma<<<grid, NTHREADS, 0, stream>>>(x, w0p, b0, wB, b1, hwp, bd, bo, out, n);
}

// Round 14
// 476.958 us; speedup vs baseline: 1.0560x; 1.0560x over previous
//
#include <hip/hip_runtime.h>
#include <math.h>

#define SB 32          // samples per block (8 per wave, 4 waves)
#define NTHREADS 256

typedef short short8 __attribute__((ext_vector_type(8)));
typedef float f32x4  __attribute__((ext_vector_type(4)));

__device__ __forceinline__ unsigned short f2bf(float f) {
    unsigned int u = __builtin_bit_cast(unsigned int, f);
    unsigned int r = (u + 0x7FFFu + ((u >> 16) & 1u)) >> 16;   // RNE
    return (unsigned short)r;
}
__device__ __forceinline__ float bf2f(unsigned short h) {
    unsigned int u = ((unsigned int)h) << 16;
    return __builtin_bit_cast(float, u);
}
__device__ __forceinline__ unsigned pack2(unsigned short lo, unsigned short hi) {
    return (unsigned)lo | ((unsigned)hi << 16);
}
__device__ __forceinline__ float softplus_f(float z) {
    return z > 15.f ? z : log1pf(expf(z));
}
__device__ __forceinline__ float fast_tanh(float z) {
    const float e = __builtin_amdgcn_exp2f(z * 2.8853900817779268f);
    return fmaf(-2.f, __builtin_amdgcn_rcpf(e + 1.f), 1.f);
}

// ---------------- prep: identical r11 layout ----------------
// wB (uint4 slots): nt*1024 + [hi: ks*64+l | lo: 512+ks*64+l]
// slot element i: B[k][n], k = ks*32 + (l>>4)*8 + i, n = nt*16 + (l&15)
__global__ void prep(const float* __restrict__ W1, const float* __restrict__ W0,
                     const float* __restrict__ Wd, const float* __restrict__ Wo,
                     const float* __restrict__ Wv,
                     unsigned short* __restrict__ wB,
                     float4* __restrict__ w0p, float4* __restrict__ hwp)
{
    int idx = blockIdx.x * blockDim.x + threadIdx.x;
    if (idx < 256) {
        w0p[idx] = make_float4(W0[idx], W0[256 + idx], W0[512 + idx], W0[768 + idx]);
        hwp[idx] = make_float4(Wd[2 * idx], Wd[2 * idx + 1], Wo[idx], Wv[idx]);
    }
    if (idx < 8192) {
        const int l  = idx & 63;
        const int ks = (idx >> 6) & 7;
        const int nt = idx >> 9;
        const int k0 = ks * 32 + (l >> 4) * 8;
        const int n  = nt * 16 + (l & 15);
        const int hbase = (nt * 1024 + ks * 64 + l) * 8;
        const int lbase = (nt * 1024 + 512 + ks * 64 + l) * 8;
        #pragma unroll
        for (int i = 0; i < 8; ++i) {
            const float f = W1[(k0 + i) * 256 + n];
            const unsigned short hi = f2bf(f);
            const unsigned short lo = f2bf(f - bf2f(hi));
            wB[hbase + i] = hi;
            wB[lbase + i] = lo;
        }
    }
}

// scalar per-sample dynamics solve + output write (r11 body, unchanged)
__device__ __forceinline__ void solve_write(
    const float* __restrict__ x, float* __restrict__ out, int sg,
    float phd0, float phd1, float phoo,
    float pad0, float pad1, float pao, float pav,
    float pbd0, float pbd1, float pbo, float pbv,
    float bd0, float bd1, float bo0)
{
    const float u    = x[sg * 6 + 2];
    const float vv   = x[sg * 6 + 3];
    const float tau0 = x[sg * 6 + 4];
    const float tau1 = x[sg * 6 + 5];

    const float zd0 = phd0 + bd0;
    const float zd1 = phd1 + bd1;
    const float zo  = phoo + bo0;

    const float ld0 = softplus_f(zd0) + 1e-4f;
    const float ld1 = softplus_f(zd1) + 1e-4f;
    const float lo  = zo;

    const float sg0 = 1.f / (1.f + expf(-zd0));
    const float sg1 = 1.f / (1.f + expf(-zd1));

    const float ld0a = sg0 * pad0, ld0b = sg0 * pbd0;
    const float ld1a = sg1 * pad1, ld1b = sg1 * pbd1;
    const float loa  = pao,        lob  = pbo;
    const float ga   = pav,        gb   = pbv;

    const float H00 = fmaf(ld0, ld0, 1e-4f);
    const float H01 = ld0 * lo;
    const float H11 = fmaf(lo, lo, fmaf(ld1, ld1, 1e-4f));

    const float dH00a = 2.f * ld0 * ld0a, dH00b = 2.f * ld0 * ld0b;
    const float dH01a = fmaf(ld0a, lo, ld0 * loa);
    const float dH01b = fmaf(ld0b, lo, ld0 * lob);
    const float dH11a = 2.f * fmaf(lo, loa, ld1 * ld1a);
    const float dH11b = 2.f * fmaf(lo, lob, ld1 * ld1b);

    const float wa0 = fmaf(dH00a, u, dH01a * vv);
    const float wa1 = fmaf(dH01a, u, dH11a * vv);
    const float wb0 = fmaf(dH00b, u, dH01b * vv);
    const float wb1 = fmaf(dH01b, u, dH11b * vv);

    const float QFa = dH00a*u*u + 2.f*dH01a*u*vv + dH11a*vv*vv;
    const float QFb = dH00b*u*u + 2.f*dH01b*u*vv + dH11b*vv*vv;

    const float C0 = fmaf(wa0, u, wb0 * vv) - 0.5f * QFa;
    const float C1 = fmaf(wa1, u, wb1 * vv) - 0.5f * QFb;

    const float r0 = tau0 - C0 - ga;
    const float r1 = tau1 - C1 - gb;

    const float det = fmaf(H00, H11, -H01 * H01);
    const float inv = 1.f / det;
    const float qdd0 = (H11 * r0 - H01 * r1) * inv;
    const float qdd1 = (H00 * r1 - H01 * r0) * inv;

    float2* o = reinterpret_cast<float2*>(&out[sg * 6]);
    o[0] = make_float2(u, vv);
    o[1] = make_float2(qdd0, qdd1);
    o[2] = make_float2(0.f, 0.f);
}

// A rows (16): frag1 = { h_hi(s0..7) rows 0-7 | h_lo(s0..7) rows 8-15 }
//              frag2 = { ta  (s0..7) rows 0-7 | tb  (s0..7) rows 8-15 }
// Lane l: row = l&15 -> sample s = row&7, isLo = row>=8; k = ks*32 + (l>>4)*8 + i.
// Each lane computes its own row directly: NO exchange, NO selects.
__global__ __launch_bounds__(NTHREADS, 3)
void lode_mfma(const float* __restrict__ x,
               const float4* __restrict__ w0p, const float* __restrict__ b0,
               const unsigned short* __restrict__ wB,
               const float* __restrict__ b1,
               const float4* __restrict__ hwp,
               const float* __restrict__ bd, const float* __restrict__ bo,
               float* __restrict__ out, int n)
{
    __shared__ uint4 S[2048];   // 32 KB B double-buffer

    const int tid  = threadIdx.x;
    const int wave = tid >> 6;
    const int lane = tid & 63;
    const int r15  = lane & 15;
    const int s    = r15 & 7;
    const bool isLo = (r15 >= 8);
    const int kg   = lane >> 4;

    // ---------------- phase 1: direct per-row A fragments ----------------
    int sg1 = blockIdx.x * SB + wave * 8 + s;
    if (sg1 >= n) sg1 = n - 1;
    const float qq0 = x[sg1 * 6 + 0];
    const float qq1 = x[sg1 * 6 + 1];
    // one sincos per lane; partner (same sample, other half) via xor8
    float ss_, cc_;
    sincosf(isLo ? qq1 : qq0, &ss_, &cc_);
    const float ss_o = __shfl_xor(ss_, 8);
    const float cc_o = __shfl_xor(cc_, 8);
    const float sn0 = isLo ? ss_o : ss_;
    const float cs0 = isLo ? cc_o : cc_;
    const float sn1 = isLo ? ss_ : ss_o;
    const float cs1 = isLo ? cc_ : cc_o;
    const float sA = isLo ? sn1 : sn0;   // tangent basis: lo-rows carry tb (angle 1)
    const float cA = isLo ? cs1 : cs0;

    short8 aF1[8], aF2[8];
    #pragma unroll
    for (int ks = 0; ks < 8; ++ks) {
        unsigned e1[4], e2[4];
        #pragma unroll
        for (int p = 0; p < 4; ++p) {
            const int j0 = ks * 32 + kg * 8 + 2 * p;
            const float4 wa = w0p[j0];
            const float4 wb = w0p[j0 + 1];
            const float2 bb = *reinterpret_cast<const float2*>(&b0[j0]);
            float z0 = bb.x;
            z0 = fmaf(cs0, wa.x, z0); z0 = fmaf(cs1, wa.y, z0);
            z0 = fmaf(sn0, wa.z, z0); z0 = fmaf(sn1, wa.w, z0);
            float z1 = bb.y;
            z1 = fmaf(cs0, wb.x, z1); z1 = fmaf(cs1, wb.y, z1);
            z1 = fmaf(sn0, wb.z, z1); z1 = fmaf(sn1, wb.w, z1);
            const float h0 = fast_tanh(z0);
            const float h1 = fast_tanh(z1);
            const unsigned short h0h = f2bf(h0);
            const unsigned short h1h = f2bf(h1);
            const unsigned short u0 = isLo ? f2bf(h0 - bf2f(h0h)) : h0h;
            const unsigned short u1 = isLo ? f2bf(h1 - bf2f(h1h)) : h1h;
            e1[p] = pack2(u0, u1);
            const float dt0 = fmaf(-h0, h0, 1.f);
            const float dt1 = fmaf(-h1, h1, 1.f);
            const float ua = isLo ? fmaf(-sA, wa.y, cA * wa.w)
                                  : fmaf(-sA, wa.x, cA * wa.z);
            const float ub = isLo ? fmaf(-sA, wb.y, cA * wb.w)
                                  : fmaf(-sA, wb.x, cA * wb.z);
            e2[p] = pack2(f2bf(dt0 * ua), f2bf(dt1 * ub));
        }
        aF1[ks] = __builtin_bit_cast(short8, make_uint4(e1[0], e1[1], e1[2], e1[3]));
        aF2[ks] = __builtin_bit_cast(short8, make_uint4(e2[0], e2[1], e2[2], e2[3]));
    }

    // ---------------- stage nt=0 into buffer 0 (r11 pattern) ----------------
    {
        const char* src = (const char*)wB;
        #pragma unroll
        for (int g = 0; g < 4; ++g) {
            const int chunk = g * 4 + wave;
            __builtin_amdgcn_global_load_lds(
                (const __attribute__((address_space(1))) void*)(src + chunk * 1024 + lane * 16),
                (__attribute__((address_space(3))) void*)&S[chunk * 64 + lane], 16, 0, 0);
        }
    }
    __syncthreads();

    // head partials: [head][r] ; ph = h-path (3), pt = tangent-path (4)
    float ph0[4] = {0,0,0,0}, ph1[4] = {0,0,0,0}, ph2[4] = {0,0,0,0};
    float pt0[4] = {0,0,0,0}, pt1[4] = {0,0,0,0}, pt2[4] = {0,0,0,0}, pt3[4] = {0,0,0,0};
    const int col = lane & 15;

    #pragma unroll 1
    for (int nt = 0; nt < 16; ++nt) {
        // prefetch nt+1 into the other buffer (wraps harmlessly at nt=15)
        {
            const int ntn = (nt + 1) & 15;
            const int bn  = (nt + 1) & 1;
            const char* src = (const char*)wB + ntn * 16384;
            #pragma unroll
            for (int g = 0; g < 4; ++g) {
                const int chunk = g * 4 + wave;
                __builtin_amdgcn_global_load_lds(
                    (const __attribute__((address_space(1))) void*)(src + chunk * 1024 + lane * 16),
                    (__attribute__((address_space(3))) void*)&S[bn * 1024 + chunk * 64 + lane],
                    16, 0, 0);
            }
        }

        const int ncol = nt * 16 + col;
        const float4 hw  = hwp[ncol];
        const float  b1v = b1[ncol];

        const uint4* Bb = &S[(nt & 1) * 1024];
        f32x4 c1 = {0.f,0.f,0.f,0.f};   // frag1 x W_hi
        f32x4 c2 = {0.f,0.f,0.f,0.f};   // frag1 x W_lo
        f32x4 c3 = {0.f,0.f,0.f,0.f};   // frag2 x W_hi
        f32x4 c4 = {0.f,0.f,0.f,0.f};   // frag2 x W_lo
        #pragma unroll
        for (int ks = 0; ks < 8; ++ks) {
            const short8 bh = *reinterpret_cast<const short8*>(&Bb[ks * 64 + lane]);
            const short8 bl = *reinterpret_cast<const short8*>(&Bb[512 + ks * 64 + lane]);
            c1 = __builtin_amdgcn_mfma_f32_16x16x32_bf16(aF1[ks], bh, c1, 0, 0, 0);
            c2 = __builtin_amdgcn_mfma_f32_16x16x32_bf16(aF1[ks], bl, c2, 0, 0, 0);
            c3 = __builtin_amdgcn_mfma_f32_16x16x32_bf16(aF2[ks], bh, c3, 0, 0, 0);
            c4 = __builtin_amdgcn_mfma_f32_16x16x32_bf16(aF2[ks], bl, c4, 0, 0, 0);
        }

        // ---- epilogue: hi/lo merge via single xor32; everything else lane-local ----
        // C row = (lane>>4)*4 + r : q0/q1 rows 0-7 = hi(s0-7); q2/q3 rows 8-15 = lo(s0-7).
        // xor32 pairs (q0,q2),(q1,q3) share the same samples -> zf identical in pair.
        // frag2 C: q0/q1 = ta(s0-7), q2/q3 = tb(s0-7) -> tangent is lane-local.
        #pragma unroll
        for (int r = 0; r < 4; ++r) {
            const float zsum = c1[r] + c2[r];
            const float zf   = zsum + __shfl_xor(zsum, 32) + b1v;
            const float h    = fast_tanh(zf);
            const float dt   = fmaf(-h, h, 1.f);
            const float t    = dt * (c3[r] + c4[r]);
            ph0[r] = fmaf(h, hw.x, ph0[r]);
            ph1[r] = fmaf(h, hw.y, ph1[r]);
            ph2[r] = fmaf(h, hw.z, ph2[r]);
            pt0[r] = fmaf(t, hw.x, pt0[r]);
            pt1[r] = fmaf(t, hw.y, pt1[r]);
            pt2[r] = fmaf(t, hw.z, pt2[r]);
            pt3[r] = fmaf(t, hw.w, pt3[r]);
        }
        __syncthreads();
    }

    // ---------------- column reduction over 16 cols (within each q) ----------------
    #pragma unroll
    for (int r = 0; r < 4; ++r) {
        #pragma unroll
        for (int m = 1; m < 16; m <<= 1) {
            ph0[r] += __shfl_xor(ph0[r], m);
            ph1[r] += __shfl_xor(ph1[r], m);
            ph2[r] += __shfl_xor(ph2[r], m);
            pt0[r] += __shfl_xor(pt0[r], m);
            pt1[r] += __shfl_xor(pt1[r], m);
            pt2[r] += __shfl_xor(pt2[r], m);
            pt3[r] += __shfl_xor(pt3[r], m);
        }
    }
    // tb-partials live in the xor32 partner (q2/q3); fetch before divergence
    float pb0[4], pb1[4], pb2[4], pb3[4];
    #pragma unroll
    for (int r = 0; r < 4; ++r) {
        pb0[r] = __shfl_xor(pt0[r], 32);
        pb1[r] = __shfl_xor(pt1[r], 32);
        pb2[r] = __shfl_xor(pt2[r], 32);
        pb3[r] = __shfl_xor(pt3[r], 32);
    }

    // q0 col0 solves samples 0-3; q1 col0 solves samples 4-7
    if (col == 0 && (lane >> 4) < 2) {
        const float bd0 = bd[0], bd1 = bd[1], bo0 = bo[0];
        const int base = blockIdx.x * SB + wave * 8 + (lane >> 4) * 4;
        #pragma unroll
        for (int r = 0; r < 4; ++r) {
            if (base + r < n)
                solve_write(x, out, base + r,
                            ph0[r], ph1[r], ph2[r],
                            pt0[r], pt1[r], pt2[r], pt3[r],
                            pb0[r], pb1[r], pb2[r], pb3[r],
                            bd0, bd1, bo0);
        }
    }
}

extern "C" void kernel_launch(void* const* d_in, const int* in_sizes, int n_in,
                              void* d_out, int out_size, void* d_ws, size_t ws_size,
                              hipStream_t stream) {
    // dict order: t, x, W0, b0, W1, b1, Wd, bd, Wo, bo, Wv, bv
    const float* x  = (const float*)d_in[1];
    const float* W0 = (const float*)d_in[2];
    const float* b0 = (const float*)d_in[3];
    const float* W1 = (const float*)d_in[4];
    const float* b1 = (const float*)d_in[5];
    const float* Wd = (const float*)d_in[6];
    const float* bd = (const float*)d_in[7];
    const float* Wo = (const float*)d_in[8];
    const float* bo = (const float*)d_in[9];
    const float* Wv = (const float*)d_in[10];
    float* out = (float*)d_out;

    unsigned short* wB = (unsigned short*)d_ws;                         // 256 KB
    float4* w0p = (float4*)((char*)d_ws + 262144);                      // 4 KB
    float4* hwp = (float4*)((char*)d_ws + 262144 + 4096);               // 4 KB

    const int n = in_sizes[1] / 6;

    prep<<<32, 256, 0, stream>>>(W1, W0, Wd, Wo, Wv, wB, w0p, hwp);

    const int grid = (n + SB - 1) / SB;
    lode_mfma<<<grid, NTHREADS, 0, stream>>>(x, w0p, b0, wB, b1, hwp, bd, bo, out, n);
}

// Round 16
// 317.805 us; speedup vs baseline: 1.5849x; 1.5008x over previous
//
#include <hip/hip_runtime.h>
#include <math.h>

#define SB 32          // samples per block (8 per wave, 4 waves)
#define NTHREADS 256

typedef short short8 __attribute__((ext_vector_type(8)));
typedef float f32x4  __attribute__((ext_vector_type(4)));

__device__ __forceinline__ unsigned short f2bf(float f) {
    unsigned int u = __builtin_bit_cast(unsigned int, f);
    unsigned int r = (u + 0x7FFFu + ((u >> 16) & 1u)) >> 16;   // RNE
    return (unsigned short)r;
}
__device__ __forceinline__ float bf2f(unsigned short h) {
    unsigned int u = ((unsigned int)h) << 16;
    return __builtin_bit_cast(float, u);
}
__device__ __forceinline__ unsigned pack2(unsigned short lo, unsigned short hi) {
    return (unsigned)lo | ((unsigned)hi << 16);
}
__device__ __forceinline__ float softplus_f(float z) {
    return z > 15.f ? z : log1pf(expf(z));
}
__device__ __forceinline__ float fast_tanh(float z) {
    const float e = __builtin_amdgcn_exp2f(z * 2.8853900817779268f);
    return fmaf(-2.f, __builtin_amdgcn_rcpf(e + 1.f), 1.f);
}
__device__ __forceinline__ unsigned selv(bool c, unsigned a, unsigned b) {
    return c ? a : b;
}
__device__ __forceinline__ unsigned sx(unsigned v, int m) {
    return (unsigned)__shfl_xor((int)v, m);
}

// ---------------- prep: pack W1 (split hi/lo) + W0 + head weights ----------------
// wB (uint4 slots): nt*1024 + [hi: ks*64+l | lo: 512+ks*64+l]
// slot element i: B[k][n], k = ks*32 + (l>>4)*8 + i, n = nt*16 + (l&15)
__global__ void prep(const float* __restrict__ W1, const float* __restrict__ W0,
                     const float* __restrict__ Wd, const float* __restrict__ Wo,
                     const float* __restrict__ Wv,
                     unsigned short* __restrict__ wB,
                     float4* __restrict__ w0p, float4* __restrict__ hwp)
{
    int idx = blockIdx.x * blockDim.x + threadIdx.x;
    if (idx < 256) {
        w0p[idx] = make_float4(W0[idx], W0[256 + idx], W0[512 + idx], W0[768 + idx]);
        hwp[idx] = make_float4(Wd[2 * idx], Wd[2 * idx + 1], Wo[idx], Wv[idx]);
    }
    if (idx < 8192) {
        const int l  = idx & 63;
        const int ks = (idx >> 6) & 7;
        const int nt = idx >> 9;
        const int k0 = ks * 32 + (l >> 4) * 8;
        const int n  = nt * 16 + (l & 15);
        const int hbase = (nt * 1024 + ks * 64 + l) * 8;
        const int lbase = (nt * 1024 + 512 + ks * 64 + l) * 8;
        #pragma unroll
        for (int i = 0; i < 8; ++i) {
            const float f = W1[(k0 + i) * 256 + n];
            const unsigned short hi = f2bf(f);
            const unsigned short lo = f2bf(f - bf2f(hi));
            wB[hbase + i] = hi;
            wB[lbase + i] = lo;
        }
    }
}

// Build one 16-row A fragment set (rows = rho*4+s: h_hi,h_lo,ta,tb x 4 samples).
// Identical arithmetic + exchange (xor 4/8/12) to the r9/r11-passing kernels.
__device__ __forceinline__ void build_aF(
    const float4* __restrict__ w0p, const float* __restrict__ b0,
    int kg, int rho, bool rb0, bool rb1,
    float sn0, float cs0, float sn1, float cs1, short8* aF)
{
    #pragma unroll
    for (int ks = 0; ks < 8; ++ks) {
        const int j0 = ks * 32 + kg * 8 + 2 * rho;
        const float4 wa = w0p[j0];
        const float4 wb = w0p[j0 + 1];
        const float2 bb = *reinterpret_cast<const float2*>(&b0[j0]);
        float z0 = bb.x;
        z0 = fmaf(cs0, wa.x, z0); z0 = fmaf(cs1, wa.y, z0);
        z0 = fmaf(sn0, wa.z, z0); z0 = fmaf(sn1, wa.w, z0);
        float z1 = bb.y;
        z1 = fmaf(cs0, wb.x, z1); z1 = fmaf(cs1, wb.y, z1);
        z1 = fmaf(sn0, wb.z, z1); z1 = fmaf(sn1, wb.w, z1);
        const float h0 = fast_tanh(z0);
        const float h1 = fast_tanh(z1);
        const unsigned short h0h = f2bf(h0);
        const unsigned short h1h = f2bf(h1);
        const unsigned short h0l = f2bf(h0 - bf2f(h0h));
        const unsigned short h1l = f2bf(h1 - bf2f(h1h));
        const float dt0 = fmaf(-h0, h0, 1.f);
        const float dt1 = fmaf(-h1, h1, 1.f);
        const float ta0 = dt0 * fmaf(-sn0, wa.x, cs0 * wa.z);
        const float ta1 = dt1 * fmaf(-sn0, wb.x, cs0 * wb.z);
        const float tb0 = dt0 * fmaf(-sn1, wa.y, cs1 * wa.w);
        const float tb1 = dt1 * fmaf(-sn1, wb.y, cs1 * wb.w);
        const unsigned v0 = pack2(h0h, h1h);
        const unsigned v1 = pack2(h0l, h1l);
        const unsigned v2 = pack2(f2bf(ta0), f2bf(ta1));
        const unsigned v3 = pack2(f2bf(tb0), f2bf(tb1));
        const unsigned s0 = selv(rb1, selv(rb0, v3, v2), selv(rb0, v1, v0));
        const unsigned s1 = selv(rb1, selv(rb0, v2, v3), selv(rb0, v0, v1));
        const unsigned s2 = selv(rb1, selv(rb0, v1, v0), selv(rb0, v3, v2));
        const unsigned s3 = selv(rb1, selv(rb0, v0, v1), selv(rb0, v2, v3));
        const unsigned r4  = sx(s1, 4);
        const unsigned r8  = sx(s2, 8);
        const unsigned r12 = sx(s3, 12);
        const unsigned w0 = selv(rb1, selv(rb0, r12, r8), selv(rb0, r4, s0));
        const unsigned w1 = selv(rb1, selv(rb0, r8, r12), selv(rb0, s0, r4));
        const unsigned w2 = selv(rb1, selv(rb0, r4, s0), selv(rb0, r12, r8));
        const unsigned w3 = selv(rb1, selv(rb0, s0, r4), selv(rb0, r8, r12));
        aF[ks] = __builtin_bit_cast(short8, make_uint4(w0, w1, w2, w3));
    }
}

// r9/r11's quadrant-dedup'd epilogue accumulation (1 tanh/lane/call).
__device__ __forceinline__ void epi_acc(
    const f32x4& c1, const f32x4& c2, float b1v, const float4& hw,
    bool qb0, bool qb1, bool qlt2,
    float* u0, float* u1, float* u2, float* u3)
{
    float zs[4], zf[4], zA[4];
    #pragma unroll
    for (int r = 0; r < 4; ++r) zs[r] = c1[r] + c2[r];
    #pragma unroll
    for (int r = 0; r < 4; ++r) zf[r] = zs[r] + __shfl_xor(zs[r], 16) + b1v;
    #pragma unroll
    for (int r = 0; r < 4; ++r) {
        const float zr = __shfl_xor(zf[r], 32);
        zA[r] = qlt2 ? zf[r] : zr;
    }
    const float zpick = qb1 ? (qb0 ? zA[3] : zA[2]) : (qb0 ? zA[1] : zA[0]);
    const float hq = fast_tanh(zpick);
    const float g1 = __shfl_xor(hq, 16);
    const float g2 = __shfl_xor(hq, 32);
    const float g3 = __shfl_xor(hq, 48);
    float hr[4];
    hr[0] = qb1 ? (qb0 ? g3 : g2) : (qb0 ? g1 : hq);
    hr[1] = qb1 ? (qb0 ? g2 : g3) : (qb0 ? hq : g1);
    hr[2] = qb1 ? (qb0 ? g1 : hq) : (qb0 ? g3 : g2);
    hr[3] = qb1 ? (qb0 ? hq : g1) : (qb0 ? g2 : g3);
    #pragma unroll
    for (int r = 0; r < 4; ++r) {
        const float dt  = fmaf(-hr[r], hr[r], 1.f);
        const float val = qlt2 ? hr[r] : dt * zs[r];
        u0[r] = fmaf(val, hw.x, u0[r]);
        u1[r] = fmaf(val, hw.y, u1[r]);
        u2[r] = fmaf(val, hw.z, u2[r]);
        u3[r] = fmaf(val, hw.w, u3[r]);
    }
}

// scalar per-sample dynamics solve + output write (r11 body, unchanged)
__device__ __forceinline__ void solve_write(
    const float* __restrict__ x, float* __restrict__ out, int sg,
    float phd0, float phd1, float phoo,
    float pad0, float pad1, float pao, float pav,
    float pbd0, float pbd1, float pbo, float pbv,
    float bd0, float bd1, float bo0)
{
    const float u    = x[sg * 6 + 2];
    const float vv   = x[sg * 6 + 3];
    const float tau0 = x[sg * 6 + 4];
    const float tau1 = x[sg * 6 + 5];

    const float zd0 = phd0 + bd0;
    const float zd1 = phd1 + bd1;
    const float zo  = phoo + bo0;

    const float ld0 = softplus_f(zd0) + 1e-4f;
    const float ld1 = softplus_f(zd1) + 1e-4f;
    const float lo  = zo;

    const float sg0 = 1.f / (1.f + expf(-zd0));
    const float sg1 = 1.f / (1.f + expf(-zd1));

    const float ld0a = sg0 * pad0, ld0b = sg0 * pbd0;
    const float ld1a = sg1 * pad1, ld1b = sg1 * pbd1;
    const float loa  = pao,        lob  = pbo;
    const float ga   = pav,        gb   = pbv;

    const float H00 = fmaf(ld0, ld0, 1e-4f);
    const float H01 = ld0 * lo;
    const float H11 = fmaf(lo, lo, fmaf(ld1, ld1, 1e-4f));

    const float dH00a = 2.f * ld0 * ld0a, dH00b = 2.f * ld0 * ld0b;
    const float dH01a = fmaf(ld0a, lo, ld0 * loa);
    const float dH01b = fmaf(ld0b, lo, ld0 * lob);
    const float dH11a = 2.f * fmaf(lo, loa, ld1 * ld1a);
    const float dH11b = 2.f * fmaf(lo, lob, ld1 * ld1b);

    const float wa0 = fmaf(dH00a, u, dH01a * vv);
    const float wa1 = fmaf(dH01a, u, dH11a * vv);
    const float wb0 = fmaf(dH00b, u, dH01b * vv);
    const float wb1 = fmaf(dH01b, u, dH11b * vv);

    const float QFa = dH00a*u*u + 2.f*dH01a*u*vv + dH11a*vv*vv;
    const float QFb = dH00b*u*u + 2.f*dH01b*u*vv + dH11b*vv*vv;

    const float C0 = fmaf(wa0, u, wb0 * vv) - 0.5f * QFa;
    const float C1 = fmaf(wa1, u, wb1 * vv) - 0.5f * QFb;

    const float r0 = tau0 - C0 - ga;
    const float r1 = tau1 - C1 - gb;

    const float det = fmaf(H00, H11, -H01 * H01);
    const float inv = 1.f / det;
    const float qdd0 = (H11 * r0 - H01 * r1) * inv;
    const float qdd1 = (H00 * r1 - H01 * r0) * inv;

    float2* o = reinterpret_cast<float2*>(&out[sg * 6]);
    o[0] = make_float2(u, vv);
    o[1] = make_float2(qdd0, qdd1);
    o[2] = make_float2(0.f, 0.f);
}

__global__ __launch_bounds__(NTHREADS, 2)
void lode_mfma(const float* __restrict__ x,
               const float4* __restrict__ w0p, const float* __restrict__ b0,
               const unsigned short* __restrict__ wB,
               const float* __restrict__ b1,
               const float4* __restrict__ hwp,
               const float* __restrict__ bd, const float* __restrict__ bo,
               float* __restrict__ out, int n)
{
    __shared__ uint4 S[4096];   // 64 KB: double buffer of 2-tile (32 KB) phases

    const int tid  = threadIdx.x;
    const int wave = tid >> 6;
    const int lane = tid & 63;
    const int r15  = lane & 15;
    const int s    = r15 & 3;
    const int rho  = r15 >> 2;
    const bool rb0 = (rho & 1) != 0;
    const bool rb1 = (rho & 2) != 0;
    const int kg   = lane >> 4;

    // ---------------- phase 1: two A-fragment sets (samples wave*8+s / +4+s) ----
    int sgA = blockIdx.x * SB + wave * 8 + s;
    int sgB = sgA + 4;
    if (sgA >= n) sgA = n - 1;
    if (sgB >= n) sgB = n - 1;
    const float qA0 = x[sgA * 6 + 0];
    const float qA1 = x[sgA * 6 + 1];
    const float qB0 = x[sgB * 6 + 0];
    const float qB1 = x[sgB * 6 + 1];
    float ssA, ccA, ssB, ccB;
    sincosf(rb0 ? qA1 : qA0, &ssA, &ccA);
    sincosf(rb0 ? qB1 : qB0, &ssB, &ccB);
    const float ssAo = __shfl_xor(ssA, 4), ccAo = __shfl_xor(ccA, 4);
    const float ssBo = __shfl_xor(ssB, 4), ccBo = __shfl_xor(ccB, 4);
    const float snA0 = rb0 ? ssAo : ssA, csA0 = rb0 ? ccAo : ccA;
    const float snA1 = rb0 ? ssA : ssAo, csA1 = rb0 ? ccA : ccAo;
    const float snB0 = rb0 ? ssBo : ssB, csB0 = rb0 ? ccBo : ccB;
    const float snB1 = rb0 ? ssB : ssBo, csB1 = rb0 ? ccB : ccBo;

    short8 aFA[8], aFB[8];
    build_aF(w0p, b0, kg, rho, rb0, rb1, snA0, csA0, snA1, csA1, aFA);
    build_aF(w0p, b0, kg, rho, rb0, rb1, snB0, csB0, snB1, csB1, aFB);

    // ---------------- stage phase 0 (tiles 0,1 = 32 KB) into buffer 0 ----------------
    {
        const char* src = (const char*)wB;
        #pragma unroll
        for (int g = 0; g < 8; ++g) {
            const int chunk = g * 4 + wave;   // 32 chunks x 1 KB
            __builtin_amdgcn_global_load_lds(
                (const __attribute__((address_space(1))) void*)(src + chunk * 1024 + lane * 16),
                (__attribute__((address_space(3))) void*)&S[chunk * 64 + lane], 16, 0, 0);
        }
    }
    __syncthreads();

    float uA0[4] = {0,0,0,0}, uA1[4] = {0,0,0,0}, uA2[4] = {0,0,0,0}, uA3[4] = {0,0,0,0};
    float uB0[4] = {0,0,0,0}, uB1[4] = {0,0,0,0}, uB2[4] = {0,0,0,0}, uB3[4] = {0,0,0,0};
    const int col = lane & 15;
    const int q   = lane >> 4;
    const bool qb0 = (q & 1) != 0;
    const bool qb1 = (q & 2) != 0;
    const bool qlt2 = (q < 2);

    #pragma unroll 1
    for (int ph = 0; ph < 8; ++ph) {
        // prefetch next phase (2 tiles, 32 KB) into the other buffer (wraps at ph=7)
        {
            const int pn = (ph + 1) & 7;
            const int bn = (ph + 1) & 1;
            const char* src = (const char*)wB + pn * 32768;
            #pragma unroll
            for (int g = 0; g < 8; ++g) {
                const int chunk = g * 4 + wave;
                __builtin_amdgcn_global_load_lds(
                    (const __attribute__((address_space(1))) void*)(src + chunk * 1024 + lane * 16),
                    (__attribute__((address_space(3))) void*)&S[bn * 2048 + chunk * 64 + lane],
                    16, 0, 0);
            }
        }

        // compute BOTH tiles of this phase between barriers
        #pragma unroll
        for (int sub = 0; sub < 2; ++sub) {
            const int nt = ph * 2 + sub;
            const int ncol = nt * 16 + col;
            const float4 hw  = hwp[ncol];
            const float  b1v = b1[ncol];

            const uint4* Bb = &S[(ph & 1) * 2048 + sub * 1024];
            f32x4 c1A = {0.f,0.f,0.f,0.f}, c2A = {0.f,0.f,0.f,0.f};
            f32x4 c1B = {0.f,0.f,0.f,0.f}, c2B = {0.f,0.f,0.f,0.f};
            #pragma unroll
            for (int ks = 0; ks < 8; ++ks) {
                const short8 bh = *reinterpret_cast<const short8*>(&Bb[ks * 64 + lane]);
                const short8 bl = *reinterpret_cast<const short8*>(&Bb[512 + ks * 64 + lane]);
                c1A = __builtin_amdgcn_mfma_f32_16x16x32_bf16(aFA[ks], bh, c1A, 0, 0, 0);
                c2A = __builtin_amdgcn_mfma_f32_16x16x32_bf16(aFA[ks], bl, c2A, 0, 0, 0);
                c1B = __builtin_amdgcn_mfma_f32_16x16x32_bf16(aFB[ks], bh, c1B, 0, 0, 0);
                c2B = __builtin_amdgcn_mfma_f32_16x16x32_bf16(aFB[ks], bl, c2B, 0, 0, 0);
            }

            epi_acc(c1A, c2A, b1v, hw, qb0, qb1, qlt2, uA0, uA1, uA2, uA3);
            epi_acc(c1B, c2B, b1v, hw, qb0, qb1, qlt2, uB0, uB1, uB2, uB3);
        }
        __syncthreads();
    }

    // ---------------- column reduction across the 16 cols ----------------
    #pragma unroll
    for (int r = 0; r < 4; ++r) {
        #pragma unroll
        for (int m = 1; m < 16; m <<= 1) {
            uA0[r] += __shfl_xor(uA0[r], m);
            uA1[r] += __shfl_xor(uA1[r], m);
            uA2[r] += __shfl_xor(uA2[r], m);
            uA3[r] += __shfl_xor(uA3[r], m);
            uB0[r] += __shfl_xor(uB0[r], m);
            uB1[r] += __shfl_xor(uB1[r], m);
            uB2[r] += __shfl_xor(uB2[r], m);
            uB3[r] += __shfl_xor(uB3[r], m);
        }
    }
    // gather tangent sums onto q0: pa from q2 (xor32), pb from q3 (xor48)
    float paA0[4], paA1[4], paA2[4], paA3[4], pbA0[4], pbA1[4], pbA2[4], pbA3[4];
    float paB0[4], paB1[4], paB2[4], paB3[4], pbB0[4], pbB1[4], pbB2[4], pbB3[4];
    #pragma unroll
    for (int r = 0; r < 4; ++r) {
        paA0[r] = __shfl_xor(uA0[r], 32);
        paA1[r] = __shfl_xor(uA1[r], 32);
        paA2[r] = __shfl_xor(uA2[r], 32);
        paA3[r] = __shfl_xor(uA3[r], 32);
        pbA0[r] = __shfl_xor(uA0[r], 48);
        pbA1[r] = __shfl_xor(uA1[r], 48);
        pbA2[r] = __shfl_xor(uA2[r], 48);
        pbA3[r] = __shfl_xor(uA3[r], 48);
        paB0[r] = __shfl_xor(uB0[r], 32);
        paB1[r] = __shfl_xor(uB1[r], 32);
        paB2[r] = __shfl_xor(uB2[r], 32);
        paB3[r] = __shfl_xor(uB3[r], 32);
        pbB0[r] = __shfl_xor(uB0[r], 48);
        pbB1[r] = __shfl_xor(uB1[r], 48);
        pbB2[r] = __shfl_xor(uB2[r], 48);
        pbB3[r] = __shfl_xor(uB3[r], 48);
    }

    if (lane == 0) {
        const float bd0 = bd[0], bd1 = bd[1], bo0 = bo[0];
        const int base = blockIdx.x * SB + wave * 8;
        #pragma unroll
        for (int r = 0; r < 4; ++r) {
            if (base + r < n)
                solve_write(x, out, base + r,
                            uA0[r], uA1[r], uA2[r],
                            paA0[r], paA1[r], paA2[r], paA3[r],
                            pbA0[r], pbA1[r], pbA2[r], pbA3[r], bd0, bd1, bo0);
            if (base + 4 + r < n)
                solve_write(x, out, base + 4 + r,
                            uB0[r], uB1[r], uB2[r],
                            paB0[r], paB1[r], paB2[r], paB3[r],
                            pbB0[r], pbB1[r], pbB2[r], pbB3[r], bd0, bd1, bo0);
        }
    }
}

extern "C" void kernel_launch(void* const* d_in, const int* in_sizes, int n_in,
                              void* d_out, int out_size, void* d_ws, size_t ws_size,
                              hipStream_t stream) {
    // dict order: t, x, W0, b0, W1, b1, Wd, bd, Wo, bo, Wv, bv
    const float* x  = (const float*)d_in[1];
    const float* W0 = (const float*)d_in[2];
    const float* b0 = (const float*)d_in[3];
    const float* W1 = (const float*)d_in[4];
    const float* b1 = (const float*)d_in[5];
    const float* Wd = (const float*)d_in[6];
    const float* bd = (const float*)d_in[7];
    const float* Wo = (const float*)d_in[8];
    const float* bo = (const float*)d_in[9];
    const float* Wv = (const float*)d_in[10];
    float* out = (float*)d_out;

    unsigned short* wB = (unsigned short*)d_ws;                         // 256 KB
    float4* w0p = (float4*)((char*)d_ws + 262144);                      // 4 KB
    float4* hwp = (float4*)((char*)d_ws + 262144 + 4096);               // 4 KB

    const int n = in_sizes[1] / 6;

    prep<<<32, 256, 0, stream>>>(W1, W0, Wd, Wo, Wv, wB, w0p, hwp);

    const int grid = (n + SB - 1) / SB;
    lode_mfma<<<grid, NTHREADS, 0, stream>>>(x, w0p, b0, wB, b1, hwp, bd, bo, out, n);
}

// Round 17
// 296.356 us; speedup vs baseline: 1.6996x; 1.0724x over previous
//
#include <hip/hip_runtime.h>
#include <math.h>

#define SB 32          // samples per block (8 per wave, 4 waves)
#define NTHREADS 256

typedef short short8 __attribute__((ext_vector_type(8)));
typedef float f32x4  __attribute__((ext_vector_type(4)));

__device__ __forceinline__ unsigned short f2bf(float f) {
    unsigned int u = __builtin_bit_cast(unsigned int, f);
    unsigned int r = (u + 0x7FFFu + ((u >> 16) & 1u)) >> 16;   // RNE
    return (unsigned short)r;
}
__device__ __forceinline__ float bf2f(unsigned short h) {
    unsigned int u = ((unsigned int)h) << 16;
    return __builtin_bit_cast(float, u);
}
__device__ __forceinline__ unsigned pack2(unsigned short lo, unsigned short hi) {
    return (unsigned)lo | ((unsigned)hi << 16);
}
__device__ __forceinline__ float softplus_f(float z) {
    return z > 15.f ? z : log1pf(expf(z));
}
__device__ __forceinline__ float fast_tanh(float z) {
    const float e = __builtin_amdgcn_exp2f(z * 2.8853900817779268f);
    return fmaf(-2.f, __builtin_amdgcn_rcpf(e + 1.f), 1.f);
}
__device__ __forceinline__ unsigned selv(bool c, unsigned a, unsigned b) {
    return c ? a : b;
}
__device__ __forceinline__ unsigned sx(unsigned v, int m) {
    return (unsigned)__shfl_xor((int)v, m);
}

// ---------------- prep: pack W1 (split hi/lo) + W0 + head weights ----------------
// wB (short8 slots): nt*1024 + [hi: ks*64+l | lo: 512+ks*64+l]
// slot element i: B[k][n], k = ks*32 + (l>>4)*8 + i, n = nt*16 + (l&15)
__global__ void prep(const float* __restrict__ W1, const float* __restrict__ W0,
                     const float* __restrict__ Wd, const float* __restrict__ Wo,
                     const float* __restrict__ Wv,
                     unsigned short* __restrict__ wB,
                     float4* __restrict__ w0p, float4* __restrict__ hwp)
{
    int idx = blockIdx.x * blockDim.x + threadIdx.x;
    if (idx < 256) {
        w0p[idx] = make_float4(W0[idx], W0[256 + idx], W0[512 + idx], W0[768 + idx]);
        hwp[idx] = make_float4(Wd[2 * idx], Wd[2 * idx + 1], Wo[idx], Wv[idx]);
    }
    if (idx < 8192) {
        const int l  = idx & 63;
        const int ks = (idx >> 6) & 7;
        const int nt = idx >> 9;
        const int k0 = ks * 32 + (l >> 4) * 8;
        const int n  = nt * 16 + (l & 15);
        const int hbase = (nt * 1024 + ks * 64 + l) * 8;
        const int lbase = (nt * 1024 + 512 + ks * 64 + l) * 8;
        #pragma unroll
        for (int i = 0; i < 8; ++i) {
            const float f = W1[(k0 + i) * 256 + n];
            const unsigned short hi = f2bf(f);
            const unsigned short lo = f2bf(f - bf2f(hi));
            wB[hbase + i] = hi;
            wB[lbase + i] = lo;
        }
    }
}

// Build one 16-row A fragment set (rows = rho*4+s: h_hi,h_lo,ta,tb x 4 samples).
// Identical arithmetic + exchange (xor 4/8/12) to the r9/r11-passing kernels.
__device__ __forceinline__ void build_aF(
    const float4* __restrict__ w0p, const float* __restrict__ b0,
    int kg, int rho, bool rb0, bool rb1,
    float sn0, float cs0, float sn1, float cs1, short8* aF)
{
    #pragma unroll
    for (int ks = 0; ks < 8; ++ks) {
        const int j0 = ks * 32 + kg * 8 + 2 * rho;
        const float4 wa = w0p[j0];
        const float4 wb = w0p[j0 + 1];
        const float2 bb = *reinterpret_cast<const float2*>(&b0[j0]);
        float z0 = bb.x;
        z0 = fmaf(cs0, wa.x, z0); z0 = fmaf(cs1, wa.y, z0);
        z0 = fmaf(sn0, wa.z, z0); z0 = fmaf(sn1, wa.w, z0);
        float z1 = bb.y;
        z1 = fmaf(cs0, wb.x, z1); z1 = fmaf(cs1, wb.y, z1);
        z1 = fmaf(sn0, wb.z, z1); z1 = fmaf(sn1, wb.w, z1);
        const float h0 = fast_tanh(z0);
        const float h1 = fast_tanh(z1);
        const unsigned short h0h = f2bf(h0);
        const unsigned short h1h = f2bf(h1);
        const unsigned short h0l = f2bf(h0 - bf2f(h0h));
        const unsigned short h1l = f2bf(h1 - bf2f(h1h));
        const float dt0 = fmaf(-h0, h0, 1.f);
        const float dt1 = fmaf(-h1, h1, 1.f);
        const float ta0 = dt0 * fmaf(-sn0, wa.x, cs0 * wa.z);
        const float ta1 = dt1 * fmaf(-sn0, wb.x, cs0 * wb.z);
        const float tb0 = dt0 * fmaf(-sn1, wa.y, cs1 * wa.w);
        const float tb1 = dt1 * fmaf(-sn1, wb.y, cs1 * wb.w);
        const unsigned v0 = pack2(h0h, h1h);
        const unsigned v1 = pack2(h0l, h1l);
        const unsigned v2 = pack2(f2bf(ta0), f2bf(ta1));
        const unsigned v3 = pack2(f2bf(tb0), f2bf(tb1));
        const unsigned s0 = selv(rb1, selv(rb0, v3, v2), selv(rb0, v1, v0));
        const unsigned s1 = selv(rb1, selv(rb0, v2, v3), selv(rb0, v0, v1));
        const unsigned s2 = selv(rb1, selv(rb0, v1, v0), selv(rb0, v3, v2));
        const unsigned s3 = selv(rb1, selv(rb0, v0, v1), selv(rb0, v2, v3));
        const unsigned r4  = sx(s1, 4);
        const unsigned r8  = sx(s2, 8);
        const unsigned r12 = sx(s3, 12);
        const unsigned w0 = selv(rb1, selv(rb0, r12, r8), selv(rb0, r4, s0));
        const unsigned w1 = selv(rb1, selv(rb0, r8, r12), selv(rb0, s0, r4));
        const unsigned w2 = selv(rb1, selv(rb0, r4, s0), selv(rb0, r12, r8));
        const unsigned w3 = selv(rb1, selv(rb0, s0, r4), selv(rb0, r8, r12));
        aF[ks] = __builtin_bit_cast(short8, make_uint4(w0, w1, w2, w3));
    }
}

// r9/r11's quadrant-dedup'd epilogue accumulation (1 tanh/lane/call).
__device__ __forceinline__ void epi_acc(
    const f32x4& c1, const f32x4& c2, float b1v, const float4& hw,
    bool qb0, bool qb1, bool qlt2,
    float* u0, float* u1, float* u2, float* u3)
{
    float zs[4], zf[4], zA[4];
    #pragma unroll
    for (int r = 0; r < 4; ++r) zs[r] = c1[r] + c2[r];
    #pragma unroll
    for (int r = 0; r < 4; ++r) zf[r] = zs[r] + __shfl_xor(zs[r], 16) + b1v;
    #pragma unroll
    for (int r = 0; r < 4; ++r) {
        const float zr = __shfl_xor(zf[r], 32);
        zA[r] = qlt2 ? zf[r] : zr;
    }
    const float zpick = qb1 ? (qb0 ? zA[3] : zA[2]) : (qb0 ? zA[1] : zA[0]);
    const float hq = fast_tanh(zpick);
    const float g1 = __shfl_xor(hq, 16);
    const float g2 = __shfl_xor(hq, 32);
    const float g3 = __shfl_xor(hq, 48);
    float hr[4];
    hr[0] = qb1 ? (qb0 ? g3 : g2) : (qb0 ? g1 : hq);
    hr[1] = qb1 ? (qb0 ? g2 : g3) : (qb0 ? hq : g1);
    hr[2] = qb1 ? (qb0 ? g1 : hq) : (qb0 ? g3 : g2);
    hr[3] = qb1 ? (qb0 ? hq : g1) : (qb0 ? g2 : g3);
    #pragma unroll
    for (int r = 0; r < 4; ++r) {
        const float dt  = fmaf(-hr[r], hr[r], 1.f);
        const float val = qlt2 ? hr[r] : dt * zs[r];
        u0[r] = fmaf(val, hw.x, u0[r]);
        u1[r] = fmaf(val, hw.y, u1[r]);
        u2[r] = fmaf(val, hw.z, u2[r]);
        u3[r] = fmaf(val, hw.w, u3[r]);
    }
}

// scalar per-sample dynamics solve + output write (r11 body, unchanged)
__device__ __forceinline__ void solve_write(
    const float* __restrict__ x, float* __restrict__ out, int sg,
    float phd0, float phd1, float phoo,
    float pad0, float pad1, float pao, float pav,
    float pbd0, float pbd1, float pbo, float pbv,
    float bd0, float bd1, float bo0)
{
    const float u    = x[sg * 6 + 2];
    const float vv   = x[sg * 6 + 3];
    const float tau0 = x[sg * 6 + 4];
    const float tau1 = x[sg * 6 + 5];

    const float zd0 = phd0 + bd0;
    const float zd1 = phd1 + bd1;
    const float zo  = phoo + bo0;

    const float ld0 = softplus_f(zd0) + 1e-4f;
    const float ld1 = softplus_f(zd1) + 1e-4f;
    const float lo  = zo;

    const float sg0 = 1.f / (1.f + expf(-zd0));
    const float sg1 = 1.f / (1.f + expf(-zd1));

    const float ld0a = sg0 * pad0, ld0b = sg0 * pbd0;
    const float ld1a = sg1 * pad1, ld1b = sg1 * pbd1;
    const float loa  = pao,        lob  = pbo;
    const float ga   = pav,        gb   = pbv;

    const float H00 = fmaf(ld0, ld0, 1e-4f);
    const float H01 = ld0 * lo;
    const float H11 = fmaf(lo, lo, fmaf(ld1, ld1, 1e-4f));

    const float dH00a = 2.f * ld0 * ld0a, dH00b = 2.f * ld0 * ld0b;
    const float dH01a = fmaf(ld0a, lo, ld0 * loa);
    const float dH01b = fmaf(ld0b, lo, ld0 * lob);
    const float dH11a = 2.f * fmaf(lo, loa, ld1 * ld1a);
    const float dH11b = 2.f * fmaf(lo, lob, ld1 * ld1b);

    const float wa0 = fmaf(dH00a, u, dH01a * vv);
    const float wa1 = fmaf(dH01a, u, dH11a * vv);
    const float wb0 = fmaf(dH00b, u, dH01b * vv);
    const float wb1 = fmaf(dH01b, u, dH11b * vv);

    const float QFa = dH00a*u*u + 2.f*dH01a*u*vv + dH11a*vv*vv;
    const float QFb = dH00b*u*u + 2.f*dH01b*u*vv + dH11b*vv*vv;

    const float C0 = fmaf(wa0, u, wb0 * vv) - 0.5f * QFa;
    const float C1 = fmaf(wa1, u, wb1 * vv) - 0.5f * QFb;

    const float r0 = tau0 - C0 - ga;
    const float r1 = tau1 - C1 - gb;

    const float det = fmaf(H00, H11, -H01 * H01);
    const float inv = 1.f / det;
    const float qdd0 = (H11 * r0 - H01 * r1) * inv;
    const float qdd1 = (H00 * r1 - H01 * r0) * inv;

    float2* o = reinterpret_cast<float2*>(&out[sg * 6]);
    o[0] = make_float2(u, vv);
    o[1] = make_float2(qdd0, qdd1);
    o[2] = make_float2(0.f, 0.f);
}

// r11 structure with register-streamed B: no LDS, no barriers.
// (256,1) so the bh/bl staging arrays stay in registers — r5 proved this
// dataflow bit-correct; its 654 us was pure launch_bounds(,2) spill.
__global__ __launch_bounds__(NTHREADS, 1)
void lode_mfma(const float* __restrict__ x,
               const float4* __restrict__ w0p, const float* __restrict__ b0,
               const unsigned short* __restrict__ wB,
               const float* __restrict__ b1,
               const float4* __restrict__ hwp,
               const float* __restrict__ bd, const float* __restrict__ bo,
               float* __restrict__ out, int n)
{
    const int tid  = threadIdx.x;
    const int wave = tid >> 6;
    const int lane = tid & 63;
    const int r15  = lane & 15;
    const int s    = r15 & 3;
    const int rho  = r15 >> 2;
    const bool rb0 = (rho & 1) != 0;
    const bool rb1 = (rho & 2) != 0;
    const int kg   = lane >> 4;

    // ---------------- phase 1: two A-fragment sets (samples wave*8+s / +4+s) ----
    int sgA = blockIdx.x * SB + wave * 8 + s;
    int sgB = sgA + 4;
    if (sgA >= n) sgA = n - 1;
    if (sgB >= n) sgB = n - 1;
    const float qA0 = x[sgA * 6 + 0];
    const float qA1 = x[sgA * 6 + 1];
    const float qB0 = x[sgB * 6 + 0];
    const float qB1 = x[sgB * 6 + 1];
    float ssA, ccA, ssB, ccB;
    sincosf(rb0 ? qA1 : qA0, &ssA, &ccA);
    sincosf(rb0 ? qB1 : qB0, &ssB, &ccB);
    const float ssAo = __shfl_xor(ssA, 4), ccAo = __shfl_xor(ccA, 4);
    const float ssBo = __shfl_xor(ssB, 4), ccBo = __shfl_xor(ccB, 4);
    const float snA0 = rb0 ? ssAo : ssA, csA0 = rb0 ? ccAo : ccA;
    const float snA1 = rb0 ? ssA : ssAo, csA1 = rb0 ? ccA : ccAo;
    const float snB0 = rb0 ? ssBo : ssB, csB0 = rb0 ? ccBo : ccB;
    const float snB1 = rb0 ? ssB : ssBo, csB1 = rb0 ? ccB : ccBo;

    short8 aFA[8], aFB[8];
    build_aF(w0p, b0, kg, rho, rb0, rb1, snA0, csA0, snA1, csA1, aFA);
    build_aF(w0p, b0, kg, rho, rb0, rb1, snB0, csB0, snB1, csB1, aFB);

    float uA0[4] = {0,0,0,0}, uA1[4] = {0,0,0,0}, uA2[4] = {0,0,0,0}, uA3[4] = {0,0,0,0};
    float uB0[4] = {0,0,0,0}, uB1[4] = {0,0,0,0}, uB2[4] = {0,0,0,0}, uB3[4] = {0,0,0,0};
    const int col = lane & 15;
    const int q   = lane >> 4;
    const bool qb0 = (q & 1) != 0;
    const bool qb1 = (q & 2) != 0;
    const bool qlt2 = (q < 2);

    const short8* __restrict__ W8 = reinterpret_cast<const short8*>(wB);

    #pragma unroll 1
    for (int nt = 0; nt < 16; ++nt) {
        const int base = nt * 1024 + lane;
        const int ncol = nt * 16 + col;
        const float4 hw  = hwp[ncol];
        const float  b1v = b1[ncol];

        // stream B tile L2 -> registers (r5-proven path; no LDS, no barrier)
        short8 bh[8], bl[8];
        #pragma unroll
        for (int ks = 0; ks < 8; ++ks) {
            bh[ks] = W8[base + ks * 64];
            bl[ks] = W8[base + 512 + ks * 64];
        }

        f32x4 c1A = {0.f,0.f,0.f,0.f}, c2A = {0.f,0.f,0.f,0.f};
        f32x4 c1B = {0.f,0.f,0.f,0.f}, c2B = {0.f,0.f,0.f,0.f};
        #pragma unroll
        for (int ks = 0; ks < 8; ++ks) {
            c1A = __builtin_amdgcn_mfma_f32_16x16x32_bf16(aFA[ks], bh[ks], c1A, 0, 0, 0);
            c2A = __builtin_amdgcn_mfma_f32_16x16x32_bf16(aFA[ks], bl[ks], c2A, 0, 0, 0);
            c1B = __builtin_amdgcn_mfma_f32_16x16x32_bf16(aFB[ks], bh[ks], c1B, 0, 0, 0);
            c2B = __builtin_amdgcn_mfma_f32_16x16x32_bf16(aFB[ks], bl[ks], c2B, 0, 0, 0);
        }

        epi_acc(c1A, c2A, b1v, hw, qb0, qb1, qlt2, uA0, uA1, uA2, uA3);
        epi_acc(c1B, c2B, b1v, hw, qb0, qb1, qlt2, uB0, uB1, uB2, uB3);
    }

    // ---------------- column reduction across the 16 cols ----------------
    #pragma unroll
    for (int r = 0; r < 4; ++r) {
        #pragma unroll
        for (int m = 1; m < 16; m <<= 1) {
            uA0[r] += __shfl_xor(uA0[r], m);
            uA1[r] += __shfl_xor(uA1[r], m);
            uA2[r] += __shfl_xor(uA2[r], m);
            uA3[r] += __shfl_xor(uA3[r], m);
            uB0[r] += __shfl_xor(uB0[r], m);
            uB1[r] += __shfl_xor(uB1[r], m);
            uB2[r] += __shfl_xor(uB2[r], m);
            uB3[r] += __shfl_xor(uB3[r], m);
        }
    }
    // gather tangent sums onto q0: pa from q2 (xor32), pb from q3 (xor48)
    float paA0[4], paA1[4], paA2[4], paA3[4], pbA0[4], pbA1[4], pbA2[4], pbA3[4];
    float paB0[4], paB1[4], paB2[4], paB3[4], pbB0[4], pbB1[4], pbB2[4], pbB3[4];
    #pragma unroll
    for (int r = 0; r < 4; ++r) {
        paA0[r] = __shfl_xor(uA0[r], 32);
        paA1[r] = __shfl_xor(uA1[r], 32);
        paA2[r] = __shfl_xor(uA2[r], 32);
        paA3[r] = __shfl_xor(uA3[r], 32);
        pbA0[r] = __shfl_xor(uA0[r], 48);
        pbA1[r] = __shfl_xor(uA1[r], 48);
        pbA2[r] = __shfl_xor(uA2[r], 48);
        pbA3[r] = __shfl_xor(uA3[r], 48);
        paB0[r] = __shfl_xor(uB0[r], 32);
        paB1[r] = __shfl_xor(uB1[r], 32);
        paB2[r] = __shfl_xor(uB2[r], 32);
        paB3[r] = __shfl_xor(uB3[r], 32);
        pbB0[r] = __shfl_xor(uB0[r], 48);
        pbB1[r] = __shfl_xor(uB1[r], 48);
        pbB2[r] = __shfl_xor(uB2[r], 48);
        pbB3[r] = __shfl_xor(uB3[r], 48);
    }

    if (lane == 0) {
        const float bd0 = bd[0], bd1 = bd[1], bo0 = bo[0];
        const int base = blockIdx.x * SB + wave * 8;
        #pragma unroll
        for (int r = 0; r < 4; ++r) {
            if (base + r < n)
                solve_write(x, out, base + r,
                            uA0[r], uA1[r], uA2[r],
                            paA0[r], paA1[r], paA2[r], paA3[r],
                            pbA0[r], pbA1[r], pbA2[r], pbA3[r], bd0, bd1, bo0);
            if (base + 4 + r < n)
                solve_write(x, out, base + 4 + r,
                            uB0[r], uB1[r], uB2[r],
                            paB0[r], paB1[r], paB2[r], paB3[r],
                            pbB0[r], pbB1[r], pbB2[r], pbB3[r], bd0, bd1, bo0);
        }
    }
}

extern "C" void kernel_launch(void* const* d_in, const int* in_sizes, int n_in,
                              void* d_out, int out_size, void* d_ws, size_t ws_size,
                              hipStream_t stream) {
    // dict order: t, x, W0, b0, W1, b1, Wd, bd, Wo, bo, Wv, bv
    const float* x  = (const float*)d_in[1];
    const float* W0 = (const float*)d_in[2];
    const float* b0 = (const float*)d_in[3];
    const float* W1 = (const float*)d_in[4];
    const float* b1 = (const float*)d_in[5];
    const float* Wd = (const float*)d_in[6];
    const float* bd = (const float*)d_in[7];
    const float* Wo = (const float*)d_in[8];
    const float* bo = (const float*)d_in[9];
    const float* Wv = (const float*)d_in[10];
    float* out = (float*)d_out;

    unsigned short* wB = (unsigned short*)d_ws;                         // 256 KB
    float4* w0p = (float4*)((char*)d_ws + 262144);                      // 4 KB
    float4* hwp = (float4*)((char*)d_ws + 262144 + 4096);               // 4 KB

    const int n = in_sizes[1] / 6;

    prep<<<32, 256, 0, stream>>>(W1, W0, Wd, Wo, Wv, wB, w0p, hwp);

    const int grid = (n + SB - 1) / SB;
    lode_mfma<<<grid, NTHREADS, 0, stream>>>(x, w0p, b0, wB, b1, hwp, bd, bo, out, n);
}